// Round 1
// baseline (39005.069 us; speedup 1.0000x reference)
//
#include <hip/hip_runtime.h>

// T=512, B=64, D=H=1024, gates=4096
#define TT 512
#define NB 64
#define DD 1024
#define NG 4096

typedef __attribute__((ext_vector_type(8))) __bf16 bf16x8;
typedef __attribute__((ext_vector_type(4))) float f32x4;

// workspace layout (bytes)
#define WC_OFF   0ul                       // bf16 [4096][2048]  = 16,777,216
#define HBUF_OFF 16777216ul                // bf16 [2][64][1024] = 262,144
#define BIAS_OFF (HBUF_OFF + 262144ul)     // f32  [4096]        = 16,384
#define CNT_OFF  (BIAS_OFF + 16384ul)      // int  [4][512]      = 8,192
#define XBF_OFF  (CNT_OFF + 8192ul)        // bf16 x mirror      = 67,108,864
#define WS_FULL  (XBF_OFF + 67108864ul)

__device__ __forceinline__ unsigned short f2bf(float f) {
  unsigned int u = __float_as_uint(f);
  u += 0x7fffu + ((u >> 16) & 1u);   // round-to-nearest-even
  return (unsigned short)(u >> 16);
}

__global__ void prep_kernel(const float* __restrict__ x, const float* __restrict__ h0,
                            const float* __restrict__ w_ih, const float* __restrict__ b_ih,
                            const float* __restrict__ w_hh, const float* __restrict__ b_hh,
                            unsigned char* __restrict__ ws, int use_xbf) {
  unsigned short* Wc  = (unsigned short*)(ws + WC_OFF);
  unsigned short* hb  = (unsigned short*)(ws + HBUF_OFF);
  float* bias         = (float*)(ws + BIAS_OFF);
  int* cnt            = (int*)(ws + CNT_OFF);
  unsigned short* xbf = (unsigned short*)(ws + XBF_OFF);
  long tid = (long)blockIdx.x * blockDim.x + threadIdx.x;
  long stride = (long)gridDim.x * blockDim.x;
  // W_cat[r][k] = k<1024 ? w_ih[r][k] : w_hh[r][k-1024]  (bf16)
  for (long i = tid; i < (long)NG * 2048; i += stride) {
    int r = (int)(i >> 11), k = (int)(i & 2047);
    float v = (k < 1024) ? w_ih[(long)r * 1024 + k] : w_hh[(long)r * 1024 + (k - 1024)];
    Wc[i] = f2bf(v);
  }
  for (long i = tid; i < NG; i += stride) bias[i] = b_ih[i] + b_hh[i];
  for (long i = tid; i < NB * DD; i += stride) hb[65536 + i] = f2bf(h0[i]);  // h_{-1} -> buf1
  for (long i = tid; i < 4 * TT; i += stride) cnt[i] = 0;
  if (use_xbf) {
    for (long i = tid; i < (long)TT * NB * DD; i += stride) xbf[i] = f2bf(x[i]);
  }
}

// 256 wgs (1/CU): bg = blockIdx>>6 (batch group of 16), cg = blockIdx&63 (16 h-cols).
// Each wg computes all 4 gates for its [16 batch x 16 col] tile, K=2048 fused [x_t | h].
// Weights register-resident: 8 waves K-split 256 each -> 32 x bf16x8 = 128 VGPR/lane.
__launch_bounds__(512, 2)
__global__ void lstm_kernel(const float* __restrict__ x, const float* __restrict__ c0,
                            float* __restrict__ out, unsigned char* __restrict__ ws,
                            int use_xbf) {
  __shared__ unsigned short A[16 * 2056];      // [16 rows][2048+8 pad] bf16 = 65,792 B
  __shared__ float red[8 * 16 * 64];           // per-wave partials      = 32,768 B
  __shared__ float bias_l[64];
  __shared__ float c_l[256];                   // cell state, fp32, persistent

  const unsigned short* Wc  = (const unsigned short*)(ws + WC_OFF);
  unsigned short* hb        = (unsigned short*)(ws + HBUF_OFF);
  const float* bias         = (const float*)(ws + BIAS_OFF);
  int* cnt                  = (int*)(ws + CNT_OFF);
  const unsigned short* xbf = (const unsigned short*)(ws + XBF_OFF);

  const int tid = threadIdx.x;
  const int bg = blockIdx.x >> 6;
  const int cg = blockIdx.x & 63;
  const int m0 = bg << 4;           // batch base
  const int j0 = cg << 4;           // h-col base
  const int wv = tid >> 6;          // wave 0..7 (K-chunk of 256)
  const int lane = tid & 63;
  const int ln = lane & 15;
  const int lq = lane >> 4;

  // ---- preload weights into registers (once) ----
  bf16x8 wreg[32];
  {
    const int k0 = wv * 256 + lq * 8;
#pragma unroll
    for (int c = 0; c < 4; ++c) {   // c = gate (n-tile)
      const unsigned short* wp = Wc + (long)(c * 1024 + j0 + ln) * 2048 + k0;
#pragma unroll
      for (int ks = 0; ks < 8; ++ks)
        wreg[c * 8 + ks] = *reinterpret_cast<const bf16x8*>(wp + ks * 32);
    }
  }
  if (tid < 64) bias_l[tid] = bias[(tid >> 4) * 1024 + j0 + (tid & 15)];
  if (tid < 256) c_l[tid] = c0[(m0 + (tid >> 4)) * DD + j0 + (tid & 15)];

  int* mycnt = cnt + bg * TT;

#pragma unroll 1
  for (int t = 0; t < TT; ++t) {
    unsigned short* hwr       = hb + (t & 1) * 65536;        // h_t
    const unsigned short* hrd = hb + ((t + 1) & 1) * 65536;  // h_{t-1}

    // ---- stage x_t slice into LDS cols [0,1024) (no dependency -> hides sync) ----
    if (use_xbf) {
      const unsigned short* xs = xbf + ((long)t * NB + m0) * DD;
#pragma unroll
      for (int it = 0; it < 4; ++it) {
        int cid = tid + it * 512;
        int row = cid >> 7, ci = (cid & 127) << 3;
        *(uint4*)(A + row * 2056 + ci) = *(const uint4*)(xs + row * DD + ci);
      }
    } else {
      const float* xs = x + ((long)t * NB + m0) * DD;
#pragma unroll
      for (int it = 0; it < 4; ++it) {
        int cid = tid + it * 512;
        int row = cid >> 7, ci = (cid & 127) << 3;
        const float* p = xs + row * DD + ci;
        float4 f0 = *(const float4*)p;
        float4 f1 = *(const float4*)(p + 4);
        uint4 pk;
        pk.x = (unsigned)f2bf(f0.x) | ((unsigned)f2bf(f0.y) << 16);
        pk.y = (unsigned)f2bf(f0.z) | ((unsigned)f2bf(f0.w) << 16);
        pk.z = (unsigned)f2bf(f1.x) | ((unsigned)f2bf(f1.y) << 16);
        pk.w = (unsigned)f2bf(f1.z) | ((unsigned)f2bf(f1.w) << 16);
        *(uint4*)(A + row * 2056 + ci) = pk;
      }
    }

    // ---- wait for h_{t-1} from the 64 wgs of this batch group ----
    if (t > 0) {
      if (tid == 0) {
        while (__hip_atomic_load(mycnt + (t - 1), __ATOMIC_RELAXED,
                                 __HIP_MEMORY_SCOPE_AGENT) < 64)
          __builtin_amdgcn_s_sleep(1);
      }
      __syncthreads();
      __threadfence();   // acquire: invalidate stale cached h lines
    }

    // ---- stage h_{t-1} into LDS cols [1024,2048) ----
#pragma unroll
    for (int it = 0; it < 4; ++it) {
      int cid = tid + it * 512;
      int row = cid >> 7, ci = (cid & 127) << 3;
      *(uint4*)(A + row * 2056 + 1024 + ci) = *(const uint4*)(hrd + (m0 + row) * DD + ci);
    }
    __syncthreads();

    // ---- MFMA: [16 x 2048] x [2048 x 64] partial (this wave: K-chunk 256) ----
    f32x4 acc0 = {0.f, 0.f, 0.f, 0.f}, acc1 = acc0, acc2 = acc0, acc3 = acc0;
    const unsigned short* ap = A + ln * 2056 + wv * 256 + lq * 8;
#pragma unroll
    for (int ks = 0; ks < 8; ++ks) {
      bf16x8 af = *reinterpret_cast<const bf16x8*>(ap + ks * 32);
      acc0 = __builtin_amdgcn_mfma_f32_16x16x32_bf16(af, wreg[ks],      acc0, 0, 0, 0);
      acc1 = __builtin_amdgcn_mfma_f32_16x16x32_bf16(af, wreg[8 + ks],  acc1, 0, 0, 0);
      acc2 = __builtin_amdgcn_mfma_f32_16x16x32_bf16(af, wreg[16 + ks], acc2, 0, 0, 0);
      acc3 = __builtin_amdgcn_mfma_f32_16x16x32_bf16(af, wreg[24 + ks], acc3, 0, 0, 0);
    }
    // D layout: col = lane&15, row = (lane>>4)*4 + reg
#pragma unroll
    for (int r = 0; r < 4; ++r) {
      float* rp = red + (wv * 16 + lq * 4 + r) * 64 + ln;
      rp[0] = acc0[r]; rp[16] = acc1[r]; rp[32] = acc2[r]; rp[48] = acc3[r];
    }
    __syncthreads();

    // ---- reduce 8 K-chunks, cell update, write h ----
    if (tid < 256) {
      const int mm = tid >> 4, jj = tid & 15;
      float s0 = bias_l[jj], s1 = bias_l[16 + jj], s2 = bias_l[32 + jj], s3 = bias_l[48 + jj];
#pragma unroll
      for (int w = 0; w < 8; ++w) {
        const float* rp = red + (w * 16 + mm) * 64 + jj;
        s0 += rp[0]; s1 += rp[16]; s2 += rp[32]; s3 += rp[48];
      }
      float ig = 1.f / (1.f + __expf(-s0));
      float fg = 1.f / (1.f + __expf(-s1));
      float gg = 1.f - 2.f / (__expf(2.f * s2) + 1.f);   // tanh
      float og = 1.f / (1.f + __expf(-s3));
      float cn = fg * c_l[tid] + ig * gg;
      c_l[tid] = cn;
      float hv = og * (1.f - 2.f / (__expf(2.f * cn) + 1.f));
      const int hoff = (m0 + mm) * DD + j0 + jj;
      out[(long)t * 65536 + hoff] = hv;                  // hs[t]
      hwr[hoff] = f2bf(hv);                              // bf16 mirror for next step
      if (t == TT - 1) {
        out[(long)TT * 65536 + hoff] = hv;               // h_n
        out[(long)TT * 65536 + 65536 + hoff] = cn;       // c_n
      }
    }
    __threadfence();       // release: make h writes agent-visible
    __syncthreads();
    if (tid == 0)
      __hip_atomic_fetch_add(mycnt + t, 1, __ATOMIC_RELEASE, __HIP_MEMORY_SCOPE_AGENT);
  }
}

extern "C" void kernel_launch(void* const* d_in, const int* in_sizes, int n_in,
                              void* d_out, int out_size, void* d_ws, size_t ws_size,
                              hipStream_t stream) {
  const float* x    = (const float*)d_in[0];
  const float* h0   = (const float*)d_in[1];
  const float* c0   = (const float*)d_in[2];
  const float* w_ih = (const float*)d_in[3];
  const float* b_ih = (const float*)d_in[4];
  const float* w_hh = (const float*)d_in[5];
  const float* b_hh = (const float*)d_in[6];
  float* out = (float*)d_out;
  unsigned char* ws = (unsigned char*)d_ws;
  int use_xbf = (ws_size >= WS_FULL) ? 1 : 0;

  hipLaunchKernelGGL(prep_kernel, dim3(2048), dim3(256), 0, stream,
                     x, h0, w_ih, b_ih, w_hh, b_hh, ws, use_xbf);

  void* args[] = { (void*)&x, (void*)&c0, (void*)&out, (void*)&ws, (void*)&use_xbf };
  hipLaunchCooperativeKernel(reinterpret_cast<void*>(lstm_kernel),
                             dim3(256), dim3(512), args, 0, stream);
}

// Round 3
// 3568.094 us; speedup vs baseline: 10.9316x; 10.9316x over previous
//
#include <hip/hip_runtime.h>

// T=512, B=64, D=H=1024, gates=4096
#define TT 512
#define NB 64
#define DD 1024
#define NG 4096

typedef __attribute__((ext_vector_type(8))) __bf16 bf16x8;
typedef __attribute__((ext_vector_type(4))) float f32x4;

// workspace layout (bytes)
#define WC_OFF   0ul                       // bf16 [4096][2048]  = 16,777,216
#define HBUF_OFF 16777216ul                // bf16 [2][64][1024] = 262,144
#define BIAS_OFF (HBUF_OFF + 262144ul)     // f32  [4096]        = 16,384
#define CNT_OFF  (BIAS_OFF + 16384ul)      // int  [4][512]      = 8,192
#define XBF_OFF  (CNT_OFF + 8192ul)        // bf16 x mirror      = 67,108,864
#define WS_FULL  (XBF_OFF + 67108864ul)

__device__ __forceinline__ unsigned short f2bf(float f) {
  unsigned int u = __float_as_uint(f);
  u += 0x7fffu + ((u >> 16) & 1u);   // round-to-nearest-even
  return (unsigned short)(u >> 16);
}

__global__ void prep_kernel(const float* __restrict__ x, const float* __restrict__ h0,
                            const float* __restrict__ w_ih, const float* __restrict__ b_ih,
                            const float* __restrict__ w_hh, const float* __restrict__ b_hh,
                            unsigned char* __restrict__ ws, int use_xbf) {
  unsigned short* Wc  = (unsigned short*)(ws + WC_OFF);
  unsigned short* hb  = (unsigned short*)(ws + HBUF_OFF);
  float* bias         = (float*)(ws + BIAS_OFF);
  int* cnt            = (int*)(ws + CNT_OFF);
  unsigned short* xbf = (unsigned short*)(ws + XBF_OFF);
  long tid = (long)blockIdx.x * blockDim.x + threadIdx.x;
  long stride = (long)gridDim.x * blockDim.x;
  // W_cat[r][k] = k<1024 ? w_ih[r][k] : w_hh[r][k-1024]  (bf16)
  for (long i = tid; i < (long)NG * 2048; i += stride) {
    int r = (int)(i >> 11), k = (int)(i & 2047);
    float v = (k < 1024) ? w_ih[(long)r * 1024 + k] : w_hh[(long)r * 1024 + (k - 1024)];
    Wc[i] = f2bf(v);
  }
  for (long i = tid; i < NG; i += stride) bias[i] = b_ih[i] + b_hh[i];
  for (long i = tid; i < NB * DD; i += stride) hb[65536 + i] = f2bf(h0[i]);  // h_{-1} -> buf1
  for (long i = tid; i < 4 * TT; i += stride) cnt[i] = 0;
  if (use_xbf) {
    for (long i = tid; i < (long)TT * NB * DD; i += stride) xbf[i] = f2bf(x[i]);
  }
}

// 256 wgs (1/CU): bg = blockIdx>>6 (batch group of 16), cg = blockIdx&63 (16 h-cols).
// Each wg computes all 4 gates for its [16 batch x 16 col] tile, K=2048 fused [x_t | h].
// Weights register-resident: 8 waves K-split 256 each -> 32 x bf16x8 = 128 VGPR/lane.
// Cross-wg h exchange: 32-bit relaxed agent-scope atomics only (cache-bypassing) —
// no __threadfence() => no per-step buffer_wbl2/buffer_inv L2 maintenance.
// Ordering: __syncthreads() drains vmcnt(0) on every wave (compiler-guaranteed before
// s_barrier), so the counter add after the barrier is ordered after all h publishes.
__launch_bounds__(512, 2)
__global__ void lstm_kernel(const float* __restrict__ x, const float* __restrict__ c0,
                            float* __restrict__ out, unsigned char* __restrict__ ws,
                            int use_xbf) {
  __shared__ unsigned short A[16 * 2056];      // [16 rows][2048+8 pad] bf16 = 65,792 B
  __shared__ float red[8 * 16 * 64];           // per-wave partials      = 32,768 B
  __shared__ float bias_l[64];
  __shared__ float c_l[256];                   // cell state, fp32, persistent
  __shared__ unsigned short hstage[256];       // h_t bf16 tile staging

  const unsigned short* Wc   = (const unsigned short*)(ws + WC_OFF);
  unsigned int* hb32         = (unsigned int*)(ws + HBUF_OFF);  // [2][64][512] u32
  const float* bias          = (const float*)(ws + BIAS_OFF);
  int* cnt                   = (int*)(ws + CNT_OFF);
  const unsigned short* xbf  = (const unsigned short*)(ws + XBF_OFF);

  const int tid = threadIdx.x;
  const int bg = blockIdx.x >> 6;
  const int cg = blockIdx.x & 63;
  const int m0 = bg << 4;           // batch base
  const int j0 = cg << 4;           // h-col base
  const int wv = tid >> 6;          // wave 0..7 (K-chunk of 256)
  const int lane = tid & 63;
  const int ln = lane & 15;
  const int lq = lane >> 4;

  // ---- preload weights into registers (once) ----
  bf16x8 wreg[32];
  {
    const int k0 = wv * 256 + lq * 8;
#pragma unroll
    for (int c = 0; c < 4; ++c) {   // c = gate (n-tile)
      const unsigned short* wp = Wc + (long)(c * 1024 + j0 + ln) * 2048 + k0;
#pragma unroll
      for (int ks = 0; ks < 8; ++ks)
        wreg[c * 8 + ks] = *reinterpret_cast<const bf16x8*>(wp + ks * 32);
    }
  }
  if (tid < 64) bias_l[tid] = bias[(tid >> 4) * 1024 + j0 + (tid & 15)];
  if (tid < 256) c_l[tid] = c0[(m0 + (tid >> 4)) * DD + j0 + (tid & 15)];

  int* mycnt = cnt + bg * TT;
  unsigned int* const A32 = (unsigned int*)A;   // pitch 1028 u32/row

#pragma unroll 1
  for (int t = 0; t < TT; ++t) {
    unsigned int* hwr32       = hb32 + (t & 1) * 32768;        // h_t
    const unsigned int* hrd32 = hb32 + ((t + 1) & 1) * 32768;  // h_{t-1}

    // ---- stage x_t slice into LDS cols [0,1024) (no dependency -> hides sync) ----
    if (use_xbf) {
      const unsigned short* xs = xbf + ((long)t * NB + m0) * DD;
#pragma unroll
      for (int it = 0; it < 4; ++it) {
        int cid = tid + it * 512;
        int row = cid >> 7, ci = (cid & 127) << 3;
        *(uint4*)(A + row * 2056 + ci) = *(const uint4*)(xs + row * DD + ci);
      }
    } else {
      const float* xs = x + ((long)t * NB + m0) * DD;
#pragma unroll
      for (int it = 0; it < 4; ++it) {
        int cid = tid + it * 512;
        int row = cid >> 7, ci = (cid & 127) << 3;
        const float* p = xs + row * DD + ci;
        float4 f0 = *(const float4*)p;
        float4 f1 = *(const float4*)(p + 4);
        uint4 pk;
        pk.x = (unsigned)f2bf(f0.x) | ((unsigned)f2bf(f0.y) << 16);
        pk.y = (unsigned)f2bf(f0.z) | ((unsigned)f2bf(f0.w) << 16);
        pk.z = (unsigned)f2bf(f1.x) | ((unsigned)f2bf(f1.y) << 16);
        pk.w = (unsigned)f2bf(f1.z) | ((unsigned)f2bf(f1.w) << 16);
        *(uint4*)(A + row * 2056 + ci) = pk;
      }
    }

    // ---- wait for h_{t-1} from the 64 wgs of this batch group ----
    if (t > 0) {
      if (tid == 0) {
        while (__hip_atomic_load(mycnt + (t - 1), __ATOMIC_RELAXED,
                                 __HIP_MEMORY_SCOPE_AGENT) < 64)
          __builtin_amdgcn_s_sleep(2);
      }
      __syncthreads();
    }

    // ---- stage h_{t-1} into LDS cols [1024,2048) via cache-bypassing u32 loads ----
#pragma unroll 8
    for (int it = 0; it < 16; ++it) {
      int cid = tid + it * 512;          // 0..8191
      int row = cid >> 9;                // 16 rows
      int wi = cid & 511;                // 512 u32 per row
      unsigned int v = __hip_atomic_load(hrd32 + (m0 + row) * 512 + wi,
                                         __ATOMIC_RELAXED, __HIP_MEMORY_SCOPE_AGENT);
      A32[row * 1028 + 512 + wi] = v;
    }
    __syncthreads();

    // ---- MFMA: [16 x 2048] x [2048 x 64] partial (this wave: K-chunk 256) ----
    f32x4 acc0 = {0.f, 0.f, 0.f, 0.f}, acc1 = acc0, acc2 = acc0, acc3 = acc0;
    const unsigned short* ap = A + ln * 2056 + wv * 256 + lq * 8;
#pragma unroll
    for (int ks = 0; ks < 8; ++ks) {
      bf16x8 af = *reinterpret_cast<const bf16x8*>(ap + ks * 32);
      acc0 = __builtin_amdgcn_mfma_f32_16x16x32_bf16(af, wreg[ks],      acc0, 0, 0, 0);
      acc1 = __builtin_amdgcn_mfma_f32_16x16x32_bf16(af, wreg[8 + ks],  acc1, 0, 0, 0);
      acc2 = __builtin_amdgcn_mfma_f32_16x16x32_bf16(af, wreg[16 + ks], acc2, 0, 0, 0);
      acc3 = __builtin_amdgcn_mfma_f32_16x16x32_bf16(af, wreg[24 + ks], acc3, 0, 0, 0);
    }
    // D layout: col = lane&15, row = (lane>>4)*4 + reg
#pragma unroll
    for (int r = 0; r < 4; ++r) {
      float* rp = red + (wv * 16 + lq * 4 + r) * 64 + ln;
      rp[0] = acc0[r]; rp[16] = acc1[r]; rp[32] = acc2[r]; rp[48] = acc3[r];
    }
    __syncthreads();

    // ---- reduce 8 K-chunks, cell update ----
    if (tid < 256) {
      const int mm = tid >> 4, jj = tid & 15;
      float s0 = bias_l[jj], s1 = bias_l[16 + jj], s2 = bias_l[32 + jj], s3 = bias_l[48 + jj];
#pragma unroll
      for (int w = 0; w < 8; ++w) {
        const float* rp = red + (w * 16 + mm) * 64 + jj;
        s0 += rp[0]; s1 += rp[16]; s2 += rp[32]; s3 += rp[48];
      }
      float ig = 1.f / (1.f + __expf(-s0));
      float fg = 1.f / (1.f + __expf(-s1));
      float gg = 1.f - 2.f / (__expf(2.f * s2) + 1.f);   // tanh
      float og = 1.f / (1.f + __expf(-s3));
      float cn = fg * c_l[tid] + ig * gg;
      c_l[tid] = cn;
      float hv = og * (1.f - 2.f / (__expf(2.f * cn) + 1.f));
      const int hoff = (m0 + mm) * DD + j0 + jj;
      out[(long)t * 65536 + hoff] = hv;                  // hs[t]
      hstage[tid] = f2bf(hv);                            // stage for packed publish
      if (t == TT - 1) {
        out[(long)TT * 65536 + hoff] = hv;               // h_n
        out[(long)TT * 65536 + 65536 + hoff] = cn;       // c_n
      }
    }
    __syncthreads();

    // ---- publish h_t: 128 cache-bypassing u32 stores ----
    if (tid < 128) {
      const int row = tid >> 3, wo = tid & 7;
      const unsigned short* hs = hstage + row * 16 + wo * 2;
      unsigned int v = (unsigned int)hs[0] | ((unsigned int)hs[1] << 16);
      __hip_atomic_store(hwr32 + (m0 + row) * 512 + (j0 >> 1) + wo, v,
                         __ATOMIC_RELAXED, __HIP_MEMORY_SCOPE_AGENT);
    }
    __syncthreads();   // compiler drains vmcnt(0) on all waves before s_barrier
    if (tid == 0) {
      asm volatile("s_waitcnt vmcnt(0)" ::: "memory");   // redundant belt-and-braces
      __hip_atomic_fetch_add(mycnt + t, 1, __ATOMIC_RELAXED, __HIP_MEMORY_SCOPE_AGENT);
    }
  }
}

extern "C" void kernel_launch(void* const* d_in, const int* in_sizes, int n_in,
                              void* d_out, int out_size, void* d_ws, size_t ws_size,
                              hipStream_t stream) {
  const float* x    = (const float*)d_in[0];
  const float* h0   = (const float*)d_in[1];
  const float* c0   = (const float*)d_in[2];
  const float* w_ih = (const float*)d_in[3];
  const float* b_ih = (const float*)d_in[4];
  const float* w_hh = (const float*)d_in[5];
  const float* b_hh = (const float*)d_in[6];
  float* out = (float*)d_out;
  unsigned char* ws = (unsigned char*)d_ws;
  int use_xbf = (ws_size >= WS_FULL) ? 1 : 0;

  hipLaunchKernelGGL(prep_kernel, dim3(2048), dim3(256), 0, stream,
                     x, h0, w_ih, b_ih, w_hh, b_hh, ws, use_xbf);

  void* args[] = { (void*)&x, (void*)&c0, (void*)&out, (void*)&ws, (void*)&use_xbf };
  hipLaunchCooperativeKernel(reinterpret_cast<void*>(lstm_kernel),
                             dim3(256), dim3(512), args, 0, stream);
}